// Round 1
// baseline (464.511 us; speedup 1.0000x reference)
//
#include <hip/hip_runtime.h>

// Problem constants (B,T,C,H,Dh) = (4,2048,1024,16,64); M = B*T = 8192.
#define SEQ_T 2048
#define NBATCH 4
#define CDIM 1024
#define NHEAD 16
#define MROWS 8192      // NBATCH * SEQ_T
#define QKVC 3072       // 3*CDIM

typedef unsigned short u16;
typedef __bf16 bf16x8 __attribute__((ext_vector_type(8)));
typedef float f32x4 __attribute__((ext_vector_type(4)));
typedef unsigned short u16x8 __attribute__((ext_vector_type(8)));

__device__ __forceinline__ u16 f32_to_bf16(float f) {
  union { float f; unsigned int u; } v; v.f = f;
  unsigned int u = v.u;
  unsigned int r = ((u >> 16) & 1u) + 0x7fffu;   // round-to-nearest-even
  return (u16)((u + r) >> 16);
}

__device__ __forceinline__ void gload_lds16(const u16* g, u16* l) {
  __builtin_amdgcn_global_load_lds(
      (const __attribute__((address_space(1))) void*)g,
      (__attribute__((address_space(3))) void*)l, 16, 0, 0);
}

// ---------------------------------------------------------------- cast f32 -> bf16
__global__ __launch_bounds__(256) void cast_bf16_kernel(const float* __restrict__ in,
                                                        u16* __restrict__ out, int n4) {
  int i = blockIdx.x * 256 + threadIdx.x;
  if (i >= n4) return;
  float4 v = ((const float4*)in)[i];
  ushort4 o;
  o.x = f32_to_bf16(v.x); o.y = f32_to_bf16(v.y);
  o.z = f32_to_bf16(v.z); o.w = f32_to_bf16(v.w);
  ((ushort4*)out)[i] = o;
}

// ------------------------------------------- transpose + cast: out[c][r] = in[r][c]
__global__ void transpose_cast_kernel(const float* __restrict__ in, u16* __restrict__ out,
                                      int R, int Cc) {
  __shared__ float tile[32][33];
  int c0 = blockIdx.x * 32, r0 = blockIdx.y * 32;
  int tx = threadIdx.x, ty = threadIdx.y;   // 32 x 8
  #pragma unroll
  for (int i = 0; i < 32; i += 8)
    tile[ty + i][tx] = in[(size_t)(r0 + ty + i) * Cc + c0 + tx];
  __syncthreads();
  #pragma unroll
  for (int i = 0; i < 32; i += 8)
    out[(size_t)(c0 + ty + i) * R + r0 + tx] = f32_to_bf16(tile[tx][ty + i]);
}

// ---------------------------------------------------------------- bf16 MFMA GEMM
// C[M][N] = A[M][K] * Bt[N][K]^T.  128x128 tile, BK=32, 4 waves (2x2), each wave
// owns a 64x64 output (4x4 fragments of 16x16x32 MFMA). m97-style staging via
// global_load_lds width=16.
template <typename OT>
__global__ __launch_bounds__(256)
void gemm_bt_kernel(const u16* __restrict__ A, const u16* __restrict__ Bt,
                    OT* __restrict__ C, int N, int K) {
  __shared__ u16 lA[128 * 32];
  __shared__ u16 lB[128 * 32];
  const int tid = threadIdx.x;
  const int lane = tid & 63, wid = tid >> 6;
  const int wm = wid >> 1, wn = wid & 1;
  const int l15 = lane & 15, lhi = lane >> 4;
  const int row0 = blockIdx.x * 128, col0 = blockIdx.y * 128;
  const int sr = lane >> 2;            // 0..15 : row within 16-row staging chunk
  const int sc = (lane & 3) * 8;       // 0,8,16,24 : col (halves)
  const int ca = wid * 2;              // this wave's 2 chunks (of 8 total)

  f32x4 acc[4][4] = {};

  for (int k0 = 0; k0 < K; k0 += 32) {
    #pragma unroll
    for (int c = 0; c < 2; ++c) {
      const int ch = ca + c;
      gload_lds16(A  + (size_t)(row0 + ch * 16 + sr) * K + k0 + sc, &lA[ch * 512]);
      gload_lds16(Bt + (size_t)(col0 + ch * 16 + sr) * K + k0 + sc, &lB[ch * 512]);
    }
    __syncthreads();
    bf16x8 af[4], bfr[4];
    #pragma unroll
    for (int mt = 0; mt < 4; ++mt)
      af[mt] = *(const bf16x8*)&lA[(wm * 64 + mt * 16 + l15) * 32 + lhi * 8];
    #pragma unroll
    for (int nt = 0; nt < 4; ++nt)
      bfr[nt] = *(const bf16x8*)&lB[(wn * 64 + nt * 16 + l15) * 32 + lhi * 8];
    #pragma unroll
    for (int mt = 0; mt < 4; ++mt)
      #pragma unroll
      for (int nt = 0; nt < 4; ++nt)
        acc[mt][nt] = __builtin_amdgcn_mfma_f32_16x16x32_bf16(af[mt], bfr[nt], acc[mt][nt], 0, 0, 0);
    __syncthreads();
  }

  #pragma unroll
  for (int mt = 0; mt < 4; ++mt)
    #pragma unroll
    for (int nt = 0; nt < 4; ++nt)
      #pragma unroll
      for (int r = 0; r < 4; ++r) {
        const int rr = row0 + wm * 64 + mt * 16 + lhi * 4 + r;
        const int cc = col0 + wn * 64 + nt * 16 + l15;
        float v = acc[mt][nt][r];
        if constexpr (sizeof(OT) == 2) C[(size_t)rr * N + cc] = f32_to_bf16(v);
        else                           C[(size_t)rr * N + cc] = v;
      }
}

// ---------------------------------------------------------------- flash attention
// One wave per 16 Q rows.  KV chunks of 32.  Swapped QK^T (mfma(K, Q^T)) so each
// lane owns S^T column q = lane&15 -> row softmax is register ops + 2 shfl_xor.
// P transposed through 1KB/wave LDS into A-fragment layout for mfma(P, V).
__global__ __launch_bounds__(256) void attn_kernel(const u16* __restrict__ QKV,
                                                   u16* __restrict__ Y) {
  __shared__ u16 ldsP[4 * 32 * 16];
  const int tid = threadIdx.x, lane = tid & 63, wid = tid >> 6;
  const int l15 = lane & 15, lhi = lane >> 4;
  const int qt = blockIdx.x * 4 + wid;
  const int h = blockIdx.y, b = blockIdx.z;
  const int q0 = qt * 16;
  const size_t base = (size_t)b * SEQ_T * QKVC;
  const u16* Qp = QKV + base + h * 64;
  const u16* Kp = QKV + base + CDIM + h * 64;
  const u16* Vp = QKV + base + 2 * CDIM + h * 64;
  u16* myP = &ldsP[wid * 512];

  // Q fragments (B-operand of S^T mfma): qf[i][j] = Q[q0+l15][i*32 + lhi*8 + j]
  bf16x8 qf[2];
  #pragma unroll
  for (int i = 0; i < 2; ++i)
    qf[i] = *(const bf16x8*)(Qp + (size_t)(q0 + l15) * QKVC + i * 32 + lhi * 8);

  f32x4 acc[4] = {};           // Y tile: D[q][dv], col=lane&15=dv, row=lhi*4+r=q
  float m = -__builtin_inff(), lsum = 0.f;
  const int nch = (q0 + 47) >> 5;    // ceil((q0+16)/32) causal chunk count

  for (int ic = 0; ic < nch; ++ic) {
    const int kv0 = ic * 32;
    // S^T tiles: D[kv][q] for two 16-row kv tiles
    f32x4 st[2];
    #pragma unroll
    for (int t = 0; t < 2; ++t) {
      f32x4 z = {0.f, 0.f, 0.f, 0.f};
      #pragma unroll
      for (int i = 0; i < 2; ++i) {
        bf16x8 kf = *(const bf16x8*)(Kp + (size_t)(kv0 + t * 16 + l15) * QKVC + i * 32 + lhi * 8);
        z = __builtin_amdgcn_mfma_f32_16x16x32_bf16(kf, qf[i], z, 0, 0, 0);
      }
      st[t] = z;
    }
    // scale + causal mask + row max
    const int qg = q0 + l15;
    float pmax = -__builtin_inff();
    #pragma unroll
    for (int t = 0; t < 2; ++t)
      #pragma unroll
      for (int r = 0; r < 4; ++r) {
        const int kvg = kv0 + t * 16 + lhi * 4 + r;
        float sv = st[t][r] * 0.125f;
        sv = (kvg > qg) ? -__builtin_inff() : sv;
        st[t][r] = sv;
        pmax = fmaxf(pmax, sv);
      }
    pmax = fmaxf(pmax, __shfl_xor(pmax, 16));
    pmax = fmaxf(pmax, __shfl_xor(pmax, 32));
    const float mnew = fmaxf(m, pmax);
    const float corr = __expf(m - mnew);    // first chunk: exp(-inf)=0
    float psum = 0.f;
    #pragma unroll
    for (int t = 0; t < 2; ++t)
      #pragma unroll
      for (int r = 0; r < 4; ++r) {
        const float p = __expf(st[t][r] - mnew);
        st[t][r] = p;
        psum += p;
      }
    psum += __shfl_xor(psum, 16);
    psum += __shfl_xor(psum, 32);
    lsum = lsum * corr + psum;
    m = mnew;
    // write P^T to LDS: myP[kv][q]
    #pragma unroll
    for (int t = 0; t < 2; ++t)
      #pragma unroll
      for (int r = 0; r < 4; ++r)
        myP[(t * 16 + lhi * 4 + r) * 16 + l15] = f32_to_bf16(st[t][r]);
    // broadcast corr to PV layout rows and rescale Y
    #pragma unroll
    for (int r = 0; r < 4; ++r) {
      const float cr = __shfl(corr, lhi * 4 + r, 64);
      #pragma unroll
      for (int d = 0; d < 4; ++d) acc[d][r] *= cr;
    }
    // P A-fragment: pa[j] = P[q=l15][kv=lhi*8+j]
    u16x8 pau;
    #pragma unroll
    for (int j = 0; j < 8; ++j)
      pau[j] = myP[(lhi * 8 + j) * 16 + l15];
    const bf16x8 pa = __builtin_bit_cast(bf16x8, pau);
    // V B-fragments + PV mfma per dv tile
    #pragma unroll
    for (int d = 0; d < 4; ++d) {
      u16x8 vbu;
      #pragma unroll
      for (int j = 0; j < 8; ++j)
        vbu[j] = Vp[(size_t)(kv0 + lhi * 8 + j) * QKVC + d * 16 + l15];
      acc[d] = __builtin_amdgcn_mfma_f32_16x16x32_bf16(pa, __builtin_bit_cast(bf16x8, vbu), acc[d], 0, 0, 0);
    }
  }

  // epilogue: divide by l, store Y[b][t][h*64+dv] bf16
  u16* Yp = Y + (size_t)b * SEQ_T * CDIM + h * 64;
  #pragma unroll
  for (int r = 0; r < 4; ++r) {
    const float lr = __shfl(lsum, lhi * 4 + r, 64);
    const float inv = 1.0f / lr;
    #pragma unroll
    for (int d = 0; d < 4; ++d)
      Yp[(size_t)(q0 + lhi * 4 + r) * CDIM + d * 16 + l15] = f32_to_bf16(acc[d][r] * inv);
  }
}

// ---------------------------------------------------------------- launch
extern "C" void kernel_launch(void* const* d_in, const int* in_sizes, int n_in,
                              void* d_out, int out_size, void* d_ws, size_t ws_size,
                              hipStream_t stream) {
  const float* x      = (const float*)d_in[0];
  const float* w_qkv  = (const float*)d_in[1];
  const float* w_proj = (const float*)d_in[2];
  float* out = (float*)d_out;

  u16* Xb  = (u16*)d_ws;                                // 8192*1024 bf16
  u16* Wqt = Xb  + (size_t)MROWS * CDIM;                // 3072*1024
  u16* Wpt = Wqt + (size_t)QKVC * CDIM;                 // 1024*1024
  u16* QKV = Wpt + (size_t)CDIM * CDIM;                 // 8192*3072
  u16* Yb  = QKV + (size_t)MROWS * QKVC;                // 8192*1024

  // casts / transposes
  cast_bf16_kernel<<<(MROWS * CDIM / 4 + 255) / 256, 256, 0, stream>>>(x, Xb, MROWS * CDIM / 4);
  transpose_cast_kernel<<<dim3(QKVC / 32, CDIM / 32), dim3(32, 8), 0, stream>>>(w_qkv, Wqt, CDIM, QKVC);
  transpose_cast_kernel<<<dim3(CDIM / 32, CDIM / 32), dim3(32, 8), 0, stream>>>(w_proj, Wpt, CDIM, CDIM);

  // qkv = x @ w_qkv  (bf16 out)
  gemm_bt_kernel<u16><<<dim3(MROWS / 128, QKVC / 128), 256, 0, stream>>>(Xb, Wqt, QKV, QKVC, CDIM);

  // attention
  attn_kernel<<<dim3(SEQ_T / 64, NHEAD, NBATCH), 256, 0, stream>>>(QKV, Yb);

  // out = y @ w_proj  (f32 out)
  gemm_bt_kernel<float><<<dim3(MROWS / 128, CDIM / 128), 256, 0, stream>>>(Yb, Wpt, out, CDIM, CDIM);
}

// Round 2
// 377.919 us; speedup vs baseline: 1.2291x; 1.2291x over previous
//
#include <hip/hip_runtime.h>

// Problem constants (B,T,C,H,Dh) = (4,2048,1024,16,64); M = B*T = 8192.
#define SEQ_T 2048
#define NBATCH 4
#define CDIM 1024
#define NHEAD 16
#define MROWS 8192      // NBATCH * SEQ_T
#define QKVC 3072       // 3*CDIM

typedef unsigned short u16;
typedef __bf16 bf16x8 __attribute__((ext_vector_type(8)));
typedef float f32x4 __attribute__((ext_vector_type(4)));
typedef unsigned short u16x8 __attribute__((ext_vector_type(8)));

__device__ __forceinline__ u16 f32_to_bf16(float f) {
  union { float f; unsigned int u; } v; v.f = f;
  unsigned int u = v.u;
  unsigned int r = ((u >> 16) & 1u) + 0x7fffu;   // round-to-nearest-even
  return (u16)((u + r) >> 16);
}

__device__ __forceinline__ void gload_lds16(const u16* g, u16* l) {
  __builtin_amdgcn_global_load_lds(
      (const __attribute__((address_space(1))) void*)g,
      (__attribute__((address_space(3))) void*)l, 16, 0, 0);
}

// ---------------------------------------------------------------- cast f32 -> bf16
__global__ __launch_bounds__(256) void cast_bf16_kernel(const float* __restrict__ in,
                                                        u16* __restrict__ out, int n4) {
  int i = blockIdx.x * 256 + threadIdx.x;
  if (i >= n4) return;
  float4 v = ((const float4*)in)[i];
  ushort4 o;
  o.x = f32_to_bf16(v.x); o.y = f32_to_bf16(v.y);
  o.z = f32_to_bf16(v.z); o.w = f32_to_bf16(v.w);
  ((ushort4*)out)[i] = o;
}

// ------------------------------------------- transpose + cast: out[c][r] = in[r][c]
__global__ void transpose_cast_kernel(const float* __restrict__ in, u16* __restrict__ out,
                                      int R, int Cc) {
  __shared__ float tile[32][33];
  int c0 = blockIdx.x * 32, r0 = blockIdx.y * 32;
  int tx = threadIdx.x, ty = threadIdx.y;   // 32 x 8
  #pragma unroll
  for (int i = 0; i < 32; i += 8)
    tile[ty + i][tx] = in[(size_t)(r0 + ty + i) * Cc + c0 + tx];
  __syncthreads();
  #pragma unroll
  for (int i = 0; i < 32; i += 8)
    out[(size_t)(c0 + ty + i) * R + r0 + tx] = f32_to_bf16(tile[tx][ty + i]);
}

// --------------------------------- V transpose: Vt[(b*H+h)*64+dv][t] = V[b][t][h*64+dv]
__global__ void transpose_v_kernel(const u16* __restrict__ QKV, u16* __restrict__ Vt) {
  __shared__ u16 tile[32][34];   // u16, stride 34 -> 17 banks/row, conflict-free
  const int t0 = blockIdx.x * 32, d0 = blockIdx.y * 32;
  const int bh = blockIdx.z;
  const int b = bh >> 4, h = bh & 15;
  const int tx = threadIdx.x, ty = threadIdx.y;   // 32 x 8
  const u16* Vp = QKV + (size_t)b * SEQ_T * QKVC + 2 * CDIM + h * 64;
  #pragma unroll
  for (int i = 0; i < 32; i += 8)
    tile[ty + i][tx] = Vp[(size_t)(t0 + ty + i) * QKVC + d0 + tx];
  __syncthreads();
  u16* Op = Vt + ((size_t)bh * 64 + d0) * SEQ_T + t0;
  #pragma unroll
  for (int i = 0; i < 32; i += 8)
    Op[(size_t)(ty + i) * SEQ_T + tx] = tile[tx][ty + i];
}

// ---------------------------------------------------------------- bf16 MFMA GEMM
// C[M][N] = A[M][K] * Bt[N][K]^T.  128x128 tile, BK=32, 4 waves (2x2), each wave
// owns a 64x64 output (4x4 fragments of 16x16x32 MFMA), global_load_lds staging.
template <typename OT>
__global__ __launch_bounds__(256)
void gemm_bt_kernel(const u16* __restrict__ A, const u16* __restrict__ Bt,
                    OT* __restrict__ C, int N, int K) {
  __shared__ u16 lA[128 * 32];
  __shared__ u16 lB[128 * 32];
  const int tid = threadIdx.x;
  const int lane = tid & 63, wid = tid >> 6;
  const int wm = wid >> 1, wn = wid & 1;
  const int l15 = lane & 15, lhi = lane >> 4;
  const int row0 = blockIdx.x * 128, col0 = blockIdx.y * 128;
  const int sr = lane >> 2;            // 0..15 : row within 16-row staging chunk
  const int sc = (lane & 3) * 8;       // 0,8,16,24 : col (halves)
  const int ca = wid * 2;              // this wave's 2 chunks (of 8 total)

  f32x4 acc[4][4] = {};

  for (int k0 = 0; k0 < K; k0 += 32) {
    #pragma unroll
    for (int c = 0; c < 2; ++c) {
      const int ch = ca + c;
      gload_lds16(A  + (size_t)(row0 + ch * 16 + sr) * K + k0 + sc, &lA[ch * 512]);
      gload_lds16(Bt + (size_t)(col0 + ch * 16 + sr) * K + k0 + sc, &lB[ch * 512]);
    }
    __syncthreads();
    bf16x8 af[4], bfr[4];
    #pragma unroll
    for (int mt = 0; mt < 4; ++mt)
      af[mt] = *(const bf16x8*)&lA[(wm * 64 + mt * 16 + l15) * 32 + lhi * 8];
    #pragma unroll
    for (int nt = 0; nt < 4; ++nt)
      bfr[nt] = *(const bf16x8*)&lB[(wn * 64 + nt * 16 + l15) * 32 + lhi * 8];
    #pragma unroll
    for (int mt = 0; mt < 4; ++mt)
      #pragma unroll
      for (int nt = 0; nt < 4; ++nt)
        acc[mt][nt] = __builtin_amdgcn_mfma_f32_16x16x32_bf16(af[mt], bfr[nt], acc[mt][nt], 0, 0, 0);
    __syncthreads();
  }

  #pragma unroll
  for (int mt = 0; mt < 4; ++mt)
    #pragma unroll
    for (int nt = 0; nt < 4; ++nt)
      #pragma unroll
      for (int r = 0; r < 4; ++r) {
        const int rr = row0 + wm * 64 + mt * 16 + lhi * 4 + r;
        const int cc = col0 + wn * 64 + nt * 16 + l15;
        float v = acc[mt][nt][r];
        if constexpr (sizeof(OT) == 2) C[(size_t)rr * N + cc] = f32_to_bf16(v);
        else                           C[(size_t)rr * N + cc] = v;
      }
}

// ---------------------------------------------------------------- flash attention
// One wave per 32 Q rows (2x16 sub-tiles), KV chunks of 32, no inter-wave sync.
// Swapped QK^T (mfma(K, Q^T)) -> lane owns S^T column q=lane&15; softmax is
// register ops + 2 shfl_xor.  P transposed through swizzled per-wave LDS
// (ds_write_b64 x2 + ds_read_b128, conflict-free).  V read pre-transposed
// (Vt[dv][t]) -> contiguous b128 B-fragments.
__global__ __launch_bounds__(256) void attn_kernel(const u16* __restrict__ QKV,
                                                   const u16* __restrict__ Vt,
                                                   u16* __restrict__ Y) {
  __shared__ u16 ldsP[4][2][16 * 32];   // [wave][qsub][16 q][32 kv] swizzled
  const int tid = threadIdx.x, lane = tid & 63, wid = tid >> 6;
  const int l15 = lane & 15, lhi = lane >> 4;
  const int h = blockIdx.y, b = blockIdx.z;
  const int q0 = blockIdx.x * 128 + wid * 32;
  const size_t base = (size_t)b * SEQ_T * QKVC;
  const u16* Qp  = QKV + base + h * 64;
  const u16* Kp  = QKV + base + CDIM + h * 64;
  const u16* Vtp = Vt + (size_t)(b * NHEAD + h) * 64 * SEQ_T;

  // Q frags (B-operand of S^T): qf[qs][i][j] = Q[q0+qs*16+l15][i*32+lhi*8+j]
  bf16x8 qf[2][2];
  #pragma unroll
  for (int qs = 0; qs < 2; ++qs)
    #pragma unroll
    for (int i = 0; i < 2; ++i)
      qf[qs][i] = *(const bf16x8*)(Qp + (size_t)(q0 + qs * 16 + l15) * QKVC + i * 32 + lhi * 8);

  f32x4 acc[2][4] = {};                 // [qs][dtile]: D[q][dv], row=lhi*4+r, col=l15
  float m[2]    = {-__builtin_inff(), -__builtin_inff()};
  float lsum[2] = {0.f, 0.f};
  const float SC = 0.125f * 1.44269504089f;   // 1/sqrt(64) * log2(e)
  const int nch = q0 / 32 + 1;

  for (int ic = 0; ic < nch; ++ic) {
    const int kv0 = ic * 32;
    // K frags (shared by both q sub-tiles)
    bf16x8 kf[2][2];
    #pragma unroll
    for (int t = 0; t < 2; ++t)
      #pragma unroll
      for (int i = 0; i < 2; ++i)
        kf[t][i] = *(const bf16x8*)(Kp + (size_t)(kv0 + t * 16 + l15) * QKVC + i * 32 + lhi * 8);
    // V frags from Vt (shared): vb[d][j] = V[kv0+lhi*8+j][d*16+l15]
    bf16x8 vb[4];
    #pragma unroll
    for (int d = 0; d < 4; ++d)
      vb[d] = *(const bf16x8*)(Vtp + (size_t)(d * 16 + l15) * SEQ_T + kv0 + lhi * 8);

    #pragma unroll
    for (int qs = 0; qs < 2; ++qs) {
      // S^T tiles: D[kv][q]
      f32x4 st[2];
      #pragma unroll
      for (int t = 0; t < 2; ++t) {
        f32x4 z = {0.f, 0.f, 0.f, 0.f};
        #pragma unroll
        for (int i = 0; i < 2; ++i)
          z = __builtin_amdgcn_mfma_f32_16x16x32_bf16(kf[t][i], qf[qs][i], z, 0, 0, 0);
        st[t] = z;
      }
      const int qg = q0 + qs * 16 + l15;
      float pmax = -__builtin_inff();
      #pragma unroll
      for (int t = 0; t < 2; ++t)
        #pragma unroll
        for (int r = 0; r < 4; ++r) {
          const int kvg = kv0 + t * 16 + lhi * 4 + r;
          float sv = st[t][r] * SC;               // log2-domain score
          sv = (kvg > qg) ? -__builtin_inff() : sv;
          st[t][r] = sv;
          pmax = fmaxf(pmax, sv);
        }
      pmax = fmaxf(pmax, __shfl_xor(pmax, 16));
      pmax = fmaxf(pmax, __shfl_xor(pmax, 32));
      const float mnew = fmaxf(m[qs], pmax);
      const float corr = exp2f(m[qs] - mnew);     // first chunk: exp2(-inf)=0
      float psum = 0.f;
      #pragma unroll
      for (int t = 0; t < 2; ++t)
        #pragma unroll
        for (int r = 0; r < 4; ++r) {
          const float p = exp2f(st[t][r] - mnew);
          st[t][r] = p;
          psum += p;
        }
      psum += __shfl_xor(psum, 16);
      psum += __shfl_xor(psum, 32);
      lsum[qs] = lsum[qs] * corr + psum;
      m[qs] = mnew;
      // write P (layout [q][kv], 16B-chunk XOR swizzle by q&3): two b64 writes
      char* prow = (char*)&ldsP[wid][qs][0] + l15 * 64;
      #pragma unroll
      for (int t = 0; t < 2; ++t) {
        uint2 w;
        w.x = (unsigned)f32_to_bf16(st[t][0]) | ((unsigned)f32_to_bf16(st[t][1]) << 16);
        w.y = (unsigned)f32_to_bf16(st[t][2]) | ((unsigned)f32_to_bf16(st[t][3]) << 16);
        const int chunk = (t * 2 + (lhi >> 1)) ^ (l15 & 3);
        *(uint2*)(prow + chunk * 16 + (lhi & 1) * 8) = w;
      }
      // rescale Y accumulator (corr uniform across lhi; row q = lhi*4+r)
      #pragma unroll
      for (int r = 0; r < 4; ++r) {
        const float cr = __shfl(corr, lhi * 4 + r, 64);
        #pragma unroll
        for (int d = 0; d < 4; ++d) acc[qs][d][r] *= cr;
      }
      // read P A-frag: pa[j] = P[q=l15][kv=lhi*8+j]  (one b128)
      const int rchunk = lhi ^ (l15 & 3);
      const bf16x8 pa = *(const bf16x8*)(prow + rchunk * 16);
      #pragma unroll
      for (int d = 0; d < 4; ++d)
        acc[qs][d] = __builtin_amdgcn_mfma_f32_16x16x32_bf16(pa, vb[d], acc[qs][d], 0, 0, 0);
    }
  }

  // epilogue: divide by l, store Y[b][t][h*64+dv] bf16
  u16* Yp = Y + (size_t)b * SEQ_T * CDIM + h * 64;
  #pragma unroll
  for (int qs = 0; qs < 2; ++qs)
    #pragma unroll
    for (int r = 0; r < 4; ++r) {
      const float lr = __shfl(lsum[qs], lhi * 4 + r, 64);
      const float inv = 1.0f / lr;
      #pragma unroll
      for (int d = 0; d < 4; ++d)
        Yp[(size_t)(q0 + qs * 16 + lhi * 4 + r) * CDIM + d * 16 + l15] =
            f32_to_bf16(acc[qs][d][r] * inv);
    }
}

// ---------------------------------------------------------------- launch
extern "C" void kernel_launch(void* const* d_in, const int* in_sizes, int n_in,
                              void* d_out, int out_size, void* d_ws, size_t ws_size,
                              hipStream_t stream) {
  const float* x      = (const float*)d_in[0];
  const float* w_qkv  = (const float*)d_in[1];
  const float* w_proj = (const float*)d_in[2];
  float* out = (float*)d_out;

  u16* Xb  = (u16*)d_ws;                                // 8192*1024 bf16
  u16* Wqt = Xb  + (size_t)MROWS * CDIM;                // 3072*1024
  u16* Wpt = Wqt + (size_t)QKVC * CDIM;                 // 1024*1024
  u16* QKV = Wpt + (size_t)CDIM * CDIM;                 // 8192*3072
  u16* Yb  = QKV + (size_t)MROWS * QKVC;                // 8192*1024
  u16* Vt  = Yb  + (size_t)MROWS * CDIM;                // 4096*2048 (V transposed)

  // casts / transposes
  cast_bf16_kernel<<<(MROWS * CDIM / 4 + 255) / 256, 256, 0, stream>>>(x, Xb, MROWS * CDIM / 4);
  transpose_cast_kernel<<<dim3(QKVC / 32, CDIM / 32), dim3(32, 8), 0, stream>>>(w_qkv, Wqt, CDIM, QKVC);
  transpose_cast_kernel<<<dim3(CDIM / 32, CDIM / 32), dim3(32, 8), 0, stream>>>(w_proj, Wpt, CDIM, CDIM);

  // qkv = x @ w_qkv  (bf16 out)
  gemm_bt_kernel<u16><<<dim3(MROWS / 128, QKVC / 128), 256, 0, stream>>>(Xb, Wqt, QKV, QKVC, CDIM);

  // V transpose for contiguous PV B-fragments
  transpose_v_kernel<<<dim3(SEQ_T / 32, 2, NBATCH * NHEAD), dim3(32, 8), 0, stream>>>(QKV, Vt);

  // attention
  attn_kernel<<<dim3(SEQ_T / 128, NHEAD, NBATCH), 256, 0, stream>>>(QKV, Vt, Yb);

  // out = y @ w_proj  (f32 out)
  gemm_bt_kernel<float><<<dim3(MROWS / 128, CDIM / 128), 256, 0, stream>>>(Yb, Wpt, out, CDIM, CDIM);
}

// Round 3
// 350.429 us; speedup vs baseline: 1.3255x; 1.0784x over previous
//
#include <hip/hip_runtime.h>

// Problem constants (B,T,C,H,Dh) = (4,2048,1024,16,64); M = B*T = 8192.
#define SEQ_T 2048
#define NBATCH 4
#define CDIM 1024
#define NHEAD 16
#define MROWS 8192      // NBATCH * SEQ_T
#define QKVC 3072       // 3*CDIM

typedef unsigned short u16;
typedef __bf16 bf16x8 __attribute__((ext_vector_type(8)));
typedef float f32x4 __attribute__((ext_vector_type(4)));

__device__ __forceinline__ u16 f32_to_bf16(float f) {
  union { float f; unsigned int u; } v; v.f = f;
  unsigned int u = v.u;
  unsigned int r = ((u >> 16) & 1u) + 0x7fffu;   // round-to-nearest-even
  return (u16)((u + r) >> 16);
}

__device__ __forceinline__ unsigned pack_bf16x2(float a, float b) {
  return (unsigned)f32_to_bf16(a) | ((unsigned)f32_to_bf16(b) << 16);
}

__device__ __forceinline__ void gload_lds16(const u16* g, u16* l) {
  __builtin_amdgcn_global_load_lds(
      (const __attribute__((address_space(1))) void*)g,
      (__attribute__((address_space(3))) void*)l, 16, 0, 0);
}

// ---------------------------------------------------------------- cast f32 -> bf16
__global__ __launch_bounds__(256) void cast_bf16_kernel(const float* __restrict__ in,
                                                        u16* __restrict__ out, int n4) {
  int i = blockIdx.x * 256 + threadIdx.x;
  if (i >= n4) return;
  float4 v = ((const float4*)in)[i];
  ushort4 o;
  o.x = f32_to_bf16(v.x); o.y = f32_to_bf16(v.y);
  o.z = f32_to_bf16(v.z); o.w = f32_to_bf16(v.w);
  ((ushort4*)out)[i] = o;
}

// ------------------------------------------- transpose + cast: out[c][r] = in[r][c]
__global__ void transpose_cast_kernel(const float* __restrict__ in, u16* __restrict__ out,
                                      int R, int Cc) {
  __shared__ float tile[32][33];
  int c0 = blockIdx.x * 32, r0 = blockIdx.y * 32;
  int tx = threadIdx.x, ty = threadIdx.y;   // 32 x 8
  #pragma unroll
  for (int i = 0; i < 32; i += 8)
    tile[ty + i][tx] = in[(size_t)(r0 + ty + i) * Cc + c0 + tx];
  __syncthreads();
  #pragma unroll
  for (int i = 0; i < 32; i += 8)
    out[(size_t)(c0 + ty + i) * R + r0 + tx] = f32_to_bf16(tile[tx][ty + i]);
}

// --------------------------------- V transpose: Vt[(b*H+h)*64+dv][t] = V[b][t][h*64+dv]
__global__ void transpose_v_kernel(const u16* __restrict__ QKV, u16* __restrict__ Vt) {
  __shared__ u16 tile[32][34];
  const int t0 = blockIdx.x * 32, d0 = blockIdx.y * 32;
  const int bh = blockIdx.z;
  const int b = bh >> 4, h = bh & 15;
  const int tx = threadIdx.x, ty = threadIdx.y;   // 32 x 8
  const u16* Vp = QKV + (size_t)b * SEQ_T * QKVC + 2 * CDIM + h * 64;
  #pragma unroll
  for (int i = 0; i < 32; i += 8)
    tile[ty + i][tx] = Vp[(size_t)(t0 + ty + i) * QKVC + d0 + tx];
  __syncthreads();
  u16* Op = Vt + ((size_t)bh * 64 + d0) * SEQ_T + t0;
  #pragma unroll
  for (int i = 0; i < 32; i += 8)
    Op[(size_t)(ty + i) * SEQ_T + tx] = tile[tx][ty + i];
}

// ---------------------------------------------------------------- bf16 MFMA GEMM
// C[M][N] = A[M][K] * Bt[N][K]^T.  128x128 tile, BK=32, 4 waves (2x2).
template <typename OT>
__global__ __launch_bounds__(256)
void gemm_bt_kernel(const u16* __restrict__ A, const u16* __restrict__ Bt,
                    OT* __restrict__ C, int N, int K) {
  __shared__ u16 lA[128 * 32];
  __shared__ u16 lB[128 * 32];
  const int tid = threadIdx.x;
  const int lane = tid & 63, wid = tid >> 6;
  const int wm = wid >> 1, wn = wid & 1;
  const int l15 = lane & 15, lhi = lane >> 4;
  const int row0 = blockIdx.x * 128, col0 = blockIdx.y * 128;
  const int sr = lane >> 2;
  const int sc = (lane & 3) * 8;
  const int ca = wid * 2;

  f32x4 acc[4][4] = {};

  for (int k0 = 0; k0 < K; k0 += 32) {
    #pragma unroll
    for (int c = 0; c < 2; ++c) {
      const int ch = ca + c;
      gload_lds16(A  + (size_t)(row0 + ch * 16 + sr) * K + k0 + sc, &lA[ch * 512]);
      gload_lds16(Bt + (size_t)(col0 + ch * 16 + sr) * K + k0 + sc, &lB[ch * 512]);
    }
    __syncthreads();
    bf16x8 af[4], bfr[4];
    #pragma unroll
    for (int mt = 0; mt < 4; ++mt)
      af[mt] = *(const bf16x8*)&lA[(wm * 64 + mt * 16 + l15) * 32 + lhi * 8];
    #pragma unroll
    for (int nt = 0; nt < 4; ++nt)
      bfr[nt] = *(const bf16x8*)&lB[(wn * 64 + nt * 16 + l15) * 32 + lhi * 8];
    #pragma unroll
    for (int mt = 0; mt < 4; ++mt)
      #pragma unroll
      for (int nt = 0; nt < 4; ++nt)
        acc[mt][nt] = __builtin_amdgcn_mfma_f32_16x16x32_bf16(af[mt], bfr[nt], acc[mt][nt], 0, 0, 0);
    __syncthreads();
  }

  #pragma unroll
  for (int mt = 0; mt < 4; ++mt)
    #pragma unroll
    for (int nt = 0; nt < 4; ++nt)
      #pragma unroll
      for (int r = 0; r < 4; ++r) {
        const int rr = row0 + wm * 64 + mt * 16 + lhi * 4 + r;
        const int cc = col0 + wn * 64 + nt * 16 + l15;
        float v = acc[mt][nt][r];
        if constexpr (sizeof(OT) == 2) C[(size_t)rr * N + cc] = f32_to_bf16(v);
        else                           C[(size_t)rr * N + cc] = v;
      }
}

// ---------------------------------------------------------------- flash attention
// Balanced paired jobs: wave handles 16-row jobs j and 127-j of one (b,h) ->
// every wave does ~65 chunk-units (no causal tail imbalance), K/V frags loaded
// once per chunk serve both jobs, and the two independent chains give ILP.
// Register double-buffered K/V prefetch. No max-subtraction: p = exp2(s*SC)
// directly (scores bounded << 127 in log2 domain for unit-normal inputs),
// per-lane partial row-sums reduced once at epilogue -> zero cross-lane ops
// and zero rescales in the loop.  P transposed through per-wave swizzled LDS
// (sw = (l15^(l15>>2))&3 spreads 16 rows over all 8 bank quads).
template <bool DOMASK>
__device__ __forceinline__ void attn_step(const bf16x8 (&qf)[2],
                                          const bf16x8 (&kf)[2][2],
                                          const bf16x8 (&vb)[4],
                                          f32x4 (&acc)[4], float& lsum,
                                          char* prow, int sw, int l15, int lhi,
                                          int kv0, int qg) {
  f32x4 st[2];
  #pragma unroll
  for (int t = 0; t < 2; ++t) {
    f32x4 z = {0.f, 0.f, 0.f, 0.f};
    z = __builtin_amdgcn_mfma_f32_16x16x32_bf16(kf[t][0], qf[0], z, 0, 0, 0);
    z = __builtin_amdgcn_mfma_f32_16x16x32_bf16(kf[t][1], qf[1], z, 0, 0, 0);
    st[t] = z;
  }
  const float SC = 0.125f * 1.44269504089f;   // 1/sqrt(64) * log2(e)
  #pragma unroll
  for (int t = 0; t < 2; ++t)
    #pragma unroll
    for (int r = 0; r < 4; ++r) {
      float sv = st[t][r] * SC;
      if (DOMASK) {
        const int kvg = kv0 + t * 16 + lhi * 4 + r;
        sv = (kvg > qg) ? -__builtin_inff() : sv;
      }
      const float p = exp2f(sv);
      st[t][r] = p;
      lsum += p;
    }
  #pragma unroll
  for (int t = 0; t < 2; ++t) {
    uint2 w;
    w.x = pack_bf16x2(st[t][0], st[t][1]);
    w.y = pack_bf16x2(st[t][2], st[t][3]);
    const int chunk = (t * 2 + (lhi >> 1)) ^ sw;
    *(uint2*)(prow + chunk * 16 + (lhi & 1) * 8) = w;
  }
  const int rchunk = lhi ^ sw;
  const bf16x8 pa = *(const bf16x8*)(prow + rchunk * 16);
  #pragma unroll
  for (int d = 0; d < 4; ++d)
    acc[d] = __builtin_amdgcn_mfma_f32_16x16x32_bf16(pa, vb[d], acc[d], 0, 0, 0);
}

__global__ __launch_bounds__(256) void attn_kernel(const u16* __restrict__ QKV,
                                                   const u16* __restrict__ Vt,
                                                   u16* __restrict__ Y) {
  __shared__ u16 ldsP[4][2][512];   // [wave][job][16q x 32kv] swizzled
  const int tid = threadIdx.x, lane = tid & 63, wid = tid >> 6;
  const int l15 = lane & 15, lhi = lane >> 4;
  const int sw = (l15 ^ (l15 >> 2)) & 3;
  const int h = blockIdx.y, b = blockIdx.z;
  const int pa = blockIdx.x * 4 + wid;           // pair index 0..63
  const int qA0 = pa * 16, qB0 = (127 - pa) * 16;
  const int nchA = pa / 2 + 1, nchB = (127 - pa) / 2 + 1;
  const size_t base = (size_t)b * SEQ_T * QKVC;
  const u16* Qp  = QKV + base + h * 64;
  const u16* Kp  = QKV + base + CDIM + h * 64;
  const u16* Vtp = Vt + (size_t)(b * NHEAD + h) * 64 * SEQ_T;
  char* prowA = (char*)&ldsP[wid][0][0] + l15 * 64;
  char* prowB = (char*)&ldsP[wid][1][0] + l15 * 64;

  bf16x8 qfA[2], qfB[2];
  #pragma unroll
  for (int i = 0; i < 2; ++i) {
    qfA[i] = *(const bf16x8*)(Qp + (size_t)(qA0 + l15) * QKVC + i * 32 + lhi * 8);
    qfB[i] = *(const bf16x8*)(Qp + (size_t)(qB0 + l15) * QKVC + i * 32 + lhi * 8);
  }
  const int qgA = qA0 + l15, qgB = qB0 + l15;

  f32x4 accA[4] = {}, accB[4] = {};
  float lsA = 0.f, lsB = 0.f;

  bf16x8 kfa[2][2], vba[4], kfb[2][2], vbb[4];

#define LOADCH(KV0, kf, vb)                                                     \
  {                                                                             \
    const int _kv = (KV0);                                                      \
    _Pragma("unroll") for (int t = 0; t < 2; ++t)                               \
      _Pragma("unroll") for (int i = 0; i < 2; ++i)                             \
        kf[t][i] = *(const bf16x8*)(Kp + (size_t)(_kv + t * 16 + l15) * QKVC + i * 32 + lhi * 8); \
    _Pragma("unroll") for (int d = 0; d < 4; ++d)                               \
      vb[d] = *(const bf16x8*)(Vtp + (size_t)(d * 16 + l15) * SEQ_T + _kv + lhi * 8); \
  }

#define STEPBODY(kfc, vbc, kfn, vbn)                                            \
  {                                                                             \
    if (ic + 1 < nchB) LOADCH((ic + 1) * 32, kfn, vbn);                         \
    const int kv0 = ic * 32;                                                    \
    if (ic == nchB - 1)                                                         \
      attn_step<true>(qfB, kfc, vbc, accB, lsB, prowB, sw, l15, lhi, kv0, qgB); \
    else                                                                        \
      attn_step<false>(qfB, kfc, vbc, accB, lsB, prowB, sw, l15, lhi, kv0, qgB);\
    if (ic < nchA) {                                                            \
      if (ic == nchA - 1)                                                       \
        attn_step<true>(qfA, kfc, vbc, accA, lsA, prowA, sw, l15, lhi, kv0, qgA); \
      else                                                                      \
        attn_step<false>(qfA, kfc, vbc, accA, lsA, prowA, sw, l15, lhi, kv0, qgA); \
    }                                                                           \
    ++ic;                                                                       \
  }

  int ic = 0;
  LOADCH(0, kfa, vba);
  while (true) {
    STEPBODY(kfa, vba, kfb, vbb);
    if (ic >= nchB) break;
    STEPBODY(kfb, vbb, kfa, vba);
    if (ic >= nchB) break;
  }
#undef LOADCH
#undef STEPBODY

  // epilogue: reduce per-lane partial row-sums, divide, store
  lsA += __shfl_xor(lsA, 16); lsA += __shfl_xor(lsA, 32);
  lsB += __shfl_xor(lsB, 16); lsB += __shfl_xor(lsB, 32);

  u16* Yp = Y + (size_t)b * SEQ_T * CDIM + h * 64;
  #pragma unroll
  for (int r = 0; r < 4; ++r) {
    const float lrA = __shfl(lsA, lhi * 4 + r, 64);
    const float lrB = __shfl(lsB, lhi * 4 + r, 64);
    const float ivA = 1.0f / lrA, ivB = 1.0f / lrB;
    #pragma unroll
    for (int d = 0; d < 4; ++d) {
      Yp[(size_t)(qA0 + lhi * 4 + r) * CDIM + d * 16 + l15] = f32_to_bf16(accA[d][r] * ivA);
      Yp[(size_t)(qB0 + lhi * 4 + r) * CDIM + d * 16 + l15] = f32_to_bf16(accB[d][r] * ivB);
    }
  }
}

// ---------------------------------------------------------------- launch
extern "C" void kernel_launch(void* const* d_in, const int* in_sizes, int n_in,
                              void* d_out, int out_size, void* d_ws, size_t ws_size,
                              hipStream_t stream) {
  const float* x      = (const float*)d_in[0];
  const float* w_qkv  = (const float*)d_in[1];
  const float* w_proj = (const float*)d_in[2];
  float* out = (float*)d_out;

  u16* Xb  = (u16*)d_ws;                                // 8192*1024 bf16
  u16* Wqt = Xb  + (size_t)MROWS * CDIM;                // 3072*1024
  u16* Wpt = Wqt + (size_t)QKVC * CDIM;                 // 1024*1024
  u16* QKV = Wpt + (size_t)CDIM * CDIM;                 // 8192*3072
  u16* Yb  = QKV + (size_t)MROWS * QKVC;                // 8192*1024
  u16* Vt  = Yb  + (size_t)MROWS * CDIM;                // 64*64*2048 (V transposed)

  // casts / transposes
  cast_bf16_kernel<<<(MROWS * CDIM / 4 + 255) / 256, 256, 0, stream>>>(x, Xb, MROWS * CDIM / 4);
  transpose_cast_kernel<<<dim3(QKVC / 32, CDIM / 32), dim3(32, 8), 0, stream>>>(w_qkv, Wqt, CDIM, QKVC);
  transpose_cast_kernel<<<dim3(CDIM / 32, CDIM / 32), dim3(32, 8), 0, stream>>>(w_proj, Wpt, CDIM, CDIM);

  // qkv = x @ w_qkv  (bf16 out)
  gemm_bt_kernel<u16><<<dim3(MROWS / 128, QKVC / 128), 256, 0, stream>>>(Xb, Wqt, QKV, QKVC, CDIM);

  // V transpose for contiguous PV B-fragments
  transpose_v_kernel<<<dim3(SEQ_T / 32, 2, NBATCH * NHEAD), dim3(32, 8), 0, stream>>>(QKV, Vt);

  // attention (balanced paired q-jobs)
  attn_kernel<<<dim3(16, NHEAD, NBATCH), 256, 0, stream>>>(QKV, Vt, Yb);

  // out = y @ w_proj  (f32 out)
  gemm_bt_kernel<float><<<dim3(MROWS / 128, CDIM / 128), 256, 0, stream>>>(Yb, Wpt, out, CDIM, CDIM);
}